// Round 4
// baseline (17830.771 us; speedup 1.0000x reference)
//
#include <hip/hip_runtime.h>
#include <hip/hip_bf16.h>
#include <stdint.h>
#include <math.h>

// Modern Hopfield retrieval, MFMA + producer/consumer wave specialization.
// Waves 0-3: QK (full K=512) + online softmax + Pr.  Waves 4-7: PV with
// register-prefetched patT fragments. 2 barriers per 64-pattern tile.
// B=1024, N=65536, D=512, beta=1.

#define BQ    1024
#define DD    512
#define NP    65536
#define NSTEP 10
#define NCHK  16
#define CHK   4096        // NP/NCHK
#define QB    64
#define NQB   16
#define NT    64
#define NTILES 64         // CHK/NT

typedef __attribute__((ext_vector_type(8)))  short bfrag;   // 8 bf16 = 4 VGPR
typedef __attribute__((ext_vector_type(16))) float accf;    // 32x32 accumulator

__device__ __forceinline__ unsigned short f2bf(float f) {
    uint32_t u = __float_as_uint(f);
    u += 0x7FFFu + ((u >> 16) & 1u);   // RNE
    return (unsigned short)(u >> 16);
}

// ---------------- one-time converts ----------------

__global__ __launch_bounds__(256) void conv_patterns(
    const float* __restrict__ pat_f32,
    unsigned short* __restrict__ pat, unsigned short* __restrict__ patT)
{
    __shared__ unsigned short T[64][65];
    const int t  = threadIdx.x;
    const int n0 = (blockIdx.x >> 3) * 64, d0 = (blockIdx.x & 7) * 64;
    {
        const int r = t >> 2, c0 = (t & 3) * 16;
        const float* src = pat_f32 + (size_t)(n0 + r) * DD + d0 + c0;
        unsigned short loc[16];
#pragma unroll
        for (int j = 0; j < 16; ++j) loc[j] = f2bf(src[j]);
        unsigned short* d = pat + (size_t)(n0 + r) * DD + d0 + c0;
#pragma unroll
        for (int j = 0; j < 16; ++j) d[j] = loc[j];
#pragma unroll
        for (int j = 0; j < 16; ++j) T[r][c0 + j] = loc[j];
    }
    __syncthreads();
    {
        const int dl = t >> 2, nc0 = (t & 3) * 16;
        unsigned short* dst = patT + (size_t)(d0 + dl) * NP + n0 + nc0;
#pragma unroll
        for (int j = 0; j < 16; ++j) dst[j] = T[nc0 + j][dl];
    }
}

__global__ __launch_bounds__(256) void conv_state(
    const float* __restrict__ query, float* __restrict__ stA,
    unsigned short* __restrict__ stbf)
{
    const int stride = gridDim.x * 256;
    for (int k = blockIdx.x * 256 + threadIdx.x; k < BQ * DD; k += stride) {
        float v = query[k];
        stA[k] = v; stbf[k] = f2bf(v);
    }
}

// ---------------- main pass ----------------

__global__ __launch_bounds__(512, 2) void hopf_pass(
    const unsigned short* __restrict__ pat,    // [NP][DD] bf16
    const unsigned short* __restrict__ patT,   // [DD][NP] bf16
    const unsigned short* __restrict__ stbf,   // [BQ][DD] bf16
    float* __restrict__ mpart, float* __restrict__ lpart,
    float* __restrict__ accp,                  // [NCHK][DD][BQ] f32 (out^T partials)
    int do_pv)
{
    __shared__ unsigned short PatL[2][NT * DD];   // 2 x 64 KB, source-swizzled
    __shared__ unsigned short Pr[QB * NT];        // probs bf16 [q][n], swizzled
    __shared__ float Marr[2][QB];                 // per-jn col max; reused for l merge
    __shared__ float Alr[QB];                     // rescale factor per q

    const int t  = threadIdx.x, ln = t & 63, w = t >> 6;
    const int lq = ln & 31, hi = ln >> 5;
    const int chunk = blockIdx.x, qb0 = blockIdx.y * QB;
    const size_t nbase = (size_t)chunk * CHK;
    const bool isQK = (w < 4);
    const int jn = w & 1, jq = (w >> 1) & 1;      // QK roles (waves 0-3)
    const int pw = w - 4;                          // PV wave index (waves 4-7)
    const int q  = jq * 32 + lq;                   // QK wave's query column

    // ---------- staging regs: each wave stages rows w*8 .. w*8+7 ----------
    uint4 sg[8];

    // ---------- QK state fragments: full K=512 (waves 0-3) ----------
    uint4 sfrag[32];
    if (isQK) {
        const unsigned short* sp = stbf + (size_t)(qb0 + q) * DD + hi * 8;
#pragma unroll
        for (int ks = 0; ks < 32; ++ks)
            sfrag[ks] = *reinterpret_cast<const uint4*>(sp + ks * 16);
    }

    // ---------- PV state: acc (4 dt x 2 qt), pf prefetch (4 dt x 4 ks) ----------
    accf acc[4][2];
    uint4 pf[4][4];
    if (!isQK) {
#pragma unroll
        for (int a = 0; a < 4; ++a)
#pragma unroll
            for (int b = 0; b < 2; ++b)
#pragma unroll
                for (int i = 0; i < 16; ++i) acc[a][b][i] = 0.f;
        if (do_pv) {
            // prefetch pf(0)
#pragma unroll
            for (int dt = 0; dt < 4; ++dt) {
                const size_t drow = (size_t)(pw * 128 + dt * 32 + lq);
#pragma unroll
                for (int ks = 0; ks < 4; ++ks)
                    pf[dt][ks] = *reinterpret_cast<const uint4*>(
                        patT + drow * NP + nbase + ks * 16 + hi * 8);
            }
        }
    }

    float m_run = -INFINITY, l_run = 0.f;

    // ---------- prologue staging: tile 0 -> buf0, load tile 1 into regs ----------
    {
        const unsigned short* src = pat + nbase * DD;
#pragma unroll
        for (int i = 0; i < 8; ++i) {
            const int r = w * 8 + i;
            sg[i] = *reinterpret_cast<const uint4*>(src + r * DD + ((ln * 8) ^ ((r & 7) << 3)));
        }
#pragma unroll
        for (int i = 0; i < 8; ++i) {
            const int r = w * 8 + i;
            *reinterpret_cast<uint4*>(&PatL[0][r * DD + ln * 8]) = sg[i];
        }
        const unsigned short* src1 = pat + (nbase + NT) * DD;
#pragma unroll
        for (int i = 0; i < 8; ++i) {
            const int r = w * 8 + i;
            sg[i] = *reinterpret_cast<const uint4*>(src1 + r * DD + ((ln * 8) ^ ((r & 7) << 3)));
        }
    }
    __syncthreads();

    for (int tile = 0; tile < NTILES; ++tile) {
        const int buf = tile & 1;
        accf sims;

        if (isQK) {
            // ---- QK: sims^T[32n x 32q], full K=512, 2 interleaved chains ----
            accf se, so;
#pragma unroll
            for (int i = 0; i < 16; ++i) { se[i] = 0.f; so[i] = 0.f; }
            const int n = jn * 32 + lq;
            const unsigned short* Abase = &PatL[buf][n * DD];
            const int sw = (n & 7) << 3;
#pragma unroll
            for (int ks = 0; ks < 32; ks += 2) {
                bfrag a0 = *reinterpret_cast<const bfrag*>(Abase + ((ks * 16 + hi * 8) ^ sw));
                bfrag a1 = *reinterpret_cast<const bfrag*>(Abase + (((ks + 1) * 16 + hi * 8) ^ sw));
                se = __builtin_amdgcn_mfma_f32_32x32x16_bf16(
                    a0, *reinterpret_cast<const bfrag*>(&sfrag[ks]), se, 0, 0, 0);
                so = __builtin_amdgcn_mfma_f32_32x32x16_bf16(
                    a1, *reinterpret_cast<const bfrag*>(&sfrag[ks + 1]), so, 0, 0, 0);
            }
#pragma unroll
            for (int i = 0; i < 16; ++i) sims[i] = se[i] + so[i];
            // per-q column max over this wave's 32 n-rows
            float mx = sims[0];
#pragma unroll
            for (int i = 1; i < 16; ++i) mx = fmaxf(mx, sims[i]);
            mx = fmaxf(mx, __shfl_xor(mx, 32, 64));
            if (hi == 0) Marr[jn][q] = mx;
        }
        __syncthreads();   // B1: Marr ready; PatL[buf] fully read; Pr/Alr consumed

        // ---- all waves: ds_write staged tile t+1 into buf^1 ----
        if (tile + 1 < NTILES) {
#pragma unroll
            for (int i = 0; i < 8; ++i) {
                const int r = w * 8 + i;
                *reinterpret_cast<uint4*>(&PatL[buf ^ 1][r * DD + ln * 8]) = sg[i];
            }
        }

        if (isQK) {
            // ---- softmax for this wave's 32n x 32q block ----
            const float tm    = fmaxf(Marr[0][q], Marr[1][q]);
            const float m_new = fmaxf(m_run, tm);
            const float alq   = __expf(m_run - m_new);
            float p[16];
            float psum = 0.f;
#pragma unroll
            for (int i = 0; i < 16; ++i) { p[i] = __expf(sims[i] - m_new); psum += p[i]; }
            psum += __shfl_xor(psum, 32, 64);
            l_run = l_run * alq + psum;
            m_run = m_new;
            if (hi == 0 && jn == 0) Alr[q] = alq;
#pragma unroll
            for (int r = 0; r < 4; ++r) {
                ushort4 pk;
                pk.x = f2bf(p[4 * r + 0]); pk.y = f2bf(p[4 * r + 1]);
                pk.z = f2bf(p[4 * r + 2]); pk.w = f2bf(p[4 * r + 3]);
                const int n0  = jn * 32 + 8 * r + 4 * hi;
                const int off = (q * NT + n0) ^ ((q & 7) << 3);
                *reinterpret_cast<ushort4*>(&Pr[off]) = pk;
            }
        }
        __syncthreads();   // B2: Pr/Alr ready; PatL[buf^1] staged for QK(t+1)

        // ---- all waves: issue staging loads for tile t+2 ----
        if (tile + 2 < NTILES) {
            const unsigned short* src = pat + (nbase + (size_t)(tile + 2) * NT) * DD;
#pragma unroll
            for (int i = 0; i < 8; ++i) {
                const int r = w * 8 + i;
                sg[i] = *reinterpret_cast<const uint4*>(src + r * DD + ((ln * 8) ^ ((r & 7) << 3)));
            }
        }

        if (!isQK && do_pv) {
            // ---- PV: out^T[128d x 64q] += pf(t) @ Pr(t) ----
            const float a0 = Alr[lq], a1 = Alr[32 + lq];
#pragma unroll
            for (int dt = 0; dt < 4; ++dt)
#pragma unroll
                for (int i = 0; i < 16; ++i) { acc[dt][0][i] *= a0; acc[dt][1][i] *= a1; }
#pragma unroll
            for (int ks = 0; ks < 4; ++ks) {
                bfrag b0, b1;
                {
                    const int o0 = ((lq) * NT + ks * 16 + hi * 8) ^ ((lq & 7) << 3);
                    const int o1 = ((32 + lq) * NT + ks * 16 + hi * 8) ^ (((32 + lq) & 7) << 3);
                    b0 = *reinterpret_cast<const bfrag*>(&Pr[o0]);
                    b1 = *reinterpret_cast<const bfrag*>(&Pr[o1]);
                }
#pragma unroll
                for (int dt = 0; dt < 4; ++dt) {
                    acc[dt][0] = __builtin_amdgcn_mfma_f32_32x32x16_bf16(
                        *reinterpret_cast<const bfrag*>(&pf[dt][ks]), b0, acc[dt][0], 0, 0, 0);
                    acc[dt][1] = __builtin_amdgcn_mfma_f32_32x32x16_bf16(
                        *reinterpret_cast<const bfrag*>(&pf[dt][ks]), b1, acc[dt][1], 0, 0, 0);
                }
            }
            // ---- prefetch pf for tile t+1 ----
            if (tile + 1 < NTILES) {
                const size_t ncol = nbase + (size_t)(tile + 1) * NT;
#pragma unroll
                for (int dt = 0; dt < 4; ++dt) {
                    const size_t drow = (size_t)(pw * 128 + dt * 32 + lq);
#pragma unroll
                    for (int ks = 0; ks < 4; ++ks)
                        pf[dt][ks] = *reinterpret_cast<const uint4*>(
                            patT + drow * NP + ncol + ks * 16 + hi * 8);
                }
            }
        }
    }

    // ---------- epilogue: merge l across jn, write partials ----------
    if (isQK && hi == 0) Marr[jn][q] = l_run;
    __syncthreads();
    if (isQK && jn == 0 && hi == 0) {
        mpart[chunk * BQ + qb0 + q] = m_run;
        lpart[chunk * BQ + qb0 + q] = Marr[0][q] + Marr[1][q];
    }
    if (!isQK && do_pv) {
        float* ap = accp + (size_t)chunk * DD * BQ;
#pragma unroll
        for (int dt = 0; dt < 4; ++dt)
#pragma unroll
            for (int qt = 0; qt < 2; ++qt)
#pragma unroll
                for (int i = 0; i < 16; ++i) {
                    const int dr = pw * 128 + dt * 32 + (i & 3) + 8 * (i >> 2) + 4 * hi;
                    ap[(size_t)dr * BQ + qb0 + qt * 32 + lq] = acc[dt][qt][i];
                }
    }
}

// ---------------- combine: merge chunk partials -> next state ----------------

__global__ __launch_bounds__(256) void hopf_combine(
    const float* __restrict__ mpart, const float* __restrict__ lpart,
    const float* __restrict__ accp,
    float* __restrict__ state_next, unsigned short* __restrict__ stbf_next)
{
    __shared__ float T[64][69];
    const int t  = threadIdx.x;
    const int qb = blockIdx.x, db = blockIdx.y;   // (16, 8)
    const int q  = qb * 64 + (t & 63);
    const int dg = t >> 6;                         // 0..3

    float mv[NCHK];
    float M = -INFINITY;
#pragma unroll
    for (int c = 0; c < NCHK; ++c) { mv[c] = mpart[c * BQ + q]; M = fmaxf(M, mv[c]); }
    float wx[NCHK];
    float L = 0.f;
#pragma unroll
    for (int c = 0; c < NCHK; ++c) { wx[c] = __expf(mv[c] - M); L += lpart[c * BQ + q] * wx[c]; }
    const float invL = 1.f / L;

    float v[16];
#pragma unroll
    for (int k = 0; k < 16; ++k) v[k] = 0.f;
    for (int c = 0; c < NCHK; ++c) {
        const float* ap = accp + ((size_t)c * DD + db * 64 + dg) * BQ + q;
#pragma unroll
        for (int k = 0; k < 16; ++k) v[k] = fmaf(wx[c], ap[(size_t)(4 * k) * BQ], v[k]);
    }
#pragma unroll
    for (int k = 0; k < 16; ++k) T[t & 63][dg + 4 * k] = v[k] * invL;
    __syncthreads();
    {
        const int qo = t >> 2, ds = (t & 3) * 16;
        float o[16];
#pragma unroll
        for (int j = 0; j < 16; ++j) o[j] = T[qo][ds + j];
        float* dst = state_next + (size_t)(qb * 64 + qo) * DD + db * 64 + ds;
        unsigned short* bdst = stbf_next + (size_t)(qb * 64 + qo) * DD + db * 64 + ds;
#pragma unroll
        for (int j = 0; j < 16; ++j) dst[j] = o[j];
#pragma unroll
        for (int j = 0; j < 16; ++j) bdst[j] = f2bf(o[j]);
    }
}

// ---------------- energy ----------------

__global__ __launch_bounds__(256) void hopf_energy(
    const float* __restrict__ state_cur,
    const float* __restrict__ mpart, const float* __restrict__ lpart,
    float* __restrict__ eout)
{
    const int ln = threadIdx.x & 63, w = threadIdx.x >> 6;
    const int q  = blockIdx.x * 4 + w;
    float mv[NCHK];
    float M = -INFINITY;
#pragma unroll
    for (int c = 0; c < NCHK; ++c) { mv[c] = mpart[c * BQ + q]; M = fmaxf(M, mv[c]); }
    float L = 0.f;
#pragma unroll
    for (int c = 0; c < NCHK; ++c) L += lpart[c * BQ + q] * __expf(mv[c] - M);
    float ns = 0.f;
#pragma unroll
    for (int k = 0; k < 8; ++k) {
        const float vv = state_cur[(size_t)q * DD + ln + 64 * k];
        ns = fmaf(vv, vv, ns);
    }
#pragma unroll
    for (int mk = 1; mk < 64; mk <<= 1) ns += __shfl_xor(ns, mk, 64);
    if (ln == 0) eout[q] = -(M + __logf(L)) + 0.5f * ns;   // beta = 1
}

// ---------------- launch ----------------

extern "C" void kernel_launch(void* const* d_in, const int* in_sizes, int n_in,
                              void* d_out, int out_size, void* d_ws, size_t ws_size,
                              hipStream_t stream) {
    (void)in_sizes; (void)n_in; (void)out_size; (void)ws_size;
    const float* query    = (const float*)d_in[0];   // [1024, 512]
    const float* patterns = (const float*)d_in[1];   // [65536, 512]
    float* out = (float*)d_out;

    uint8_t* ws = (uint8_t*)d_ws;
    unsigned short* pat  = (unsigned short*)ws; ws += (size_t)NP * DD * 2;   // 67 MB
    unsigned short* patT = (unsigned short*)ws; ws += (size_t)NP * DD * 2;   // 67 MB
    float* stateA = (float*)ws; ws += (size_t)BQ * DD * 4;
    float* stateB = (float*)ws; ws += (size_t)BQ * DD * 4;
    unsigned short* stbf = (unsigned short*)ws; ws += (size_t)BQ * DD * 2;
    float* mpart = (float*)ws; ws += (size_t)NCHK * BQ * 4;
    float* lpart = (float*)ws; ws += (size_t)NCHK * BQ * 4;
    float* accp  = (float*)ws; ws += (size_t)NCHK * DD * BQ * 4;             // 32 MB

    conv_patterns<<<dim3(8192), 256, 0, stream>>>(patterns, pat, patT);
    conv_state<<<dim3(512), 256, 0, stream>>>(query, stateA, stbf);

    float* energies = out + BQ * DD;
    for (int t = 0; t <= NSTEP; ++t) {
        float* cur = (t & 1) ? stateB : stateA;
        float* nxt = (t & 1) ? stateA : stateB;
        hopf_pass<<<dim3(NCHK, NQB), 512, 0, stream>>>(pat, patT, stbf, mpart, lpart,
                                                       accp, (t < NSTEP) ? 1 : 0);
        hopf_energy<<<dim3(BQ / 4), 256, 0, stream>>>(cur, mpart, lpart, energies + t * BQ);
        if (t < NSTEP)
            hopf_combine<<<dim3(NQB, 8), 256, 0, stream>>>(mpart, lpart, accp, nxt, stbf);
    }
    hipMemcpyAsync(out, stateA, (size_t)BQ * DD * 4, hipMemcpyDeviceToDevice, stream);
}

// Round 5
// 12668.947 us; speedup vs baseline: 1.4074x; 1.4074x over previous
//
#include <hip/hip_runtime.h>
#include <hip/hip_bf16.h>
#include <stdint.h>
#include <math.h>

// Modern Hopfield retrieval, MFMA + producer/consumer wave specialization.
// Waves 0-3: QK (full K=512) + online softmax + Pr.  Waves 4-7: PV with
// direct patT fragment loads (L2/L3-hot). 2 barriers per 64-pattern tile.
// amdgpu_waves_per_eu(2,2) pins the allocator at 256 VGPRs (R4 spilled at 128).
// B=1024, N=65536, D=512, beta=1.

#define BQ    1024
#define DD    512
#define NP    65536
#define NSTEP 10
#define NCHK  16
#define CHK   4096        // NP/NCHK
#define QB    64
#define NQB   16
#define NT    64
#define NTILES 64         // CHK/NT

typedef __attribute__((ext_vector_type(8)))  short bfrag;   // 8 bf16 = 4 VGPR
typedef __attribute__((ext_vector_type(16))) float accf;    // 32x32 accumulator

__device__ __forceinline__ unsigned short f2bf(float f) {
    uint32_t u = __float_as_uint(f);
    u += 0x7FFFu + ((u >> 16) & 1u);   // RNE
    return (unsigned short)(u >> 16);
}

// ---------------- one-time converts ----------------

__global__ __launch_bounds__(256) void conv_patterns(
    const float* __restrict__ pat_f32,
    unsigned short* __restrict__ pat, unsigned short* __restrict__ patT)
{
    __shared__ unsigned short T[64][65];
    const int t  = threadIdx.x;
    const int n0 = (blockIdx.x >> 3) * 64, d0 = (blockIdx.x & 7) * 64;
    {
        const int r = t >> 2, c0 = (t & 3) * 16;
        const float* src = pat_f32 + (size_t)(n0 + r) * DD + d0 + c0;
        unsigned short loc[16];
#pragma unroll
        for (int j = 0; j < 16; ++j) loc[j] = f2bf(src[j]);
        unsigned short* d = pat + (size_t)(n0 + r) * DD + d0 + c0;
#pragma unroll
        for (int j = 0; j < 16; ++j) d[j] = loc[j];
#pragma unroll
        for (int j = 0; j < 16; ++j) T[r][c0 + j] = loc[j];
    }
    __syncthreads();
    {
        const int dl = t >> 2, nc0 = (t & 3) * 16;
        unsigned short* dst = patT + (size_t)(d0 + dl) * NP + n0 + nc0;
#pragma unroll
        for (int j = 0; j < 16; ++j) dst[j] = T[nc0 + j][dl];
    }
}

__global__ __launch_bounds__(256) void conv_state(
    const float* __restrict__ query, float* __restrict__ stA,
    unsigned short* __restrict__ stbf)
{
    const int stride = gridDim.x * 256;
    for (int k = blockIdx.x * 256 + threadIdx.x; k < BQ * DD; k += stride) {
        float v = query[k];
        stA[k] = v; stbf[k] = f2bf(v);
    }
}

// ---------------- main pass ----------------

__global__ __launch_bounds__(512) __attribute__((amdgpu_waves_per_eu(2, 2)))
void hopf_pass(
    const unsigned short* __restrict__ pat,    // [NP][DD] bf16
    const unsigned short* __restrict__ patT,   // [DD][NP] bf16
    const unsigned short* __restrict__ stbf,   // [BQ][DD] bf16
    float* __restrict__ mpart, float* __restrict__ lpart,
    float* __restrict__ accp,                  // [NCHK][DD][BQ] f32 (out^T partials)
    int do_pv)
{
    __shared__ unsigned short PatL[2][NT * DD];   // 2 x 64 KB, source-swizzled
    __shared__ unsigned short Pr[QB * NT];        // probs bf16 [q][n], swizzled
    __shared__ float Marr[2][QB];                 // per-jn col max; reused for l merge
    __shared__ float Alr[QB];                     // rescale factor per q

    const int t  = threadIdx.x, ln = t & 63, w = t >> 6;
    const int lq = ln & 31, hi = ln >> 5;
    const int chunk = blockIdx.x, qb0 = blockIdx.y * QB;
    const size_t nbase = (size_t)chunk * CHK;
    const bool isQK = (w < 4);
    const int jn = w & 1, jq = (w >> 1) & 1;      // QK roles (waves 0-3)
    const int pw = w - 4;                          // PV wave index (waves 4-7)
    const int q  = jq * 32 + lq;                   // QK wave's query column

    // ---------- staging regs: each wave stages rows w*8 .. w*8+7 ----------
    uint4 sg[8];

    // ---------- QK state fragments: full K=512 (waves 0-3) ----------
    uint4 sfrag[32];
    if (isQK) {
        const unsigned short* sp = stbf + (size_t)(qb0 + q) * DD + hi * 8;
#pragma unroll
        for (int ks = 0; ks < 32; ++ks)
            sfrag[ks] = *reinterpret_cast<const uint4*>(sp + ks * 16);
    }

    // ---------- PV state: acc (4 dt x 2 qt) ----------
    accf acc[4][2];
    if (!isQK) {
#pragma unroll
        for (int a = 0; a < 4; ++a)
#pragma unroll
            for (int b = 0; b < 2; ++b)
#pragma unroll
                for (int i = 0; i < 16; ++i) acc[a][b][i] = 0.f;
    }

    float m_run = -INFINITY, l_run = 0.f;

    // ---------- prologue staging: tile 0 -> buf0, load tile 1 into regs ----------
    {
        const unsigned short* src = pat + nbase * DD;
#pragma unroll
        for (int i = 0; i < 8; ++i) {
            const int r = w * 8 + i;
            sg[i] = *reinterpret_cast<const uint4*>(src + r * DD + ((ln * 8) ^ ((r & 7) << 3)));
        }
#pragma unroll
        for (int i = 0; i < 8; ++i) {
            const int r = w * 8 + i;
            *reinterpret_cast<uint4*>(&PatL[0][r * DD + ln * 8]) = sg[i];
        }
        const unsigned short* src1 = pat + (nbase + NT) * DD;
#pragma unroll
        for (int i = 0; i < 8; ++i) {
            const int r = w * 8 + i;
            sg[i] = *reinterpret_cast<const uint4*>(src1 + r * DD + ((ln * 8) ^ ((r & 7) << 3)));
        }
    }
    __syncthreads();

    for (int tile = 0; tile < NTILES; ++tile) {
        const int buf = tile & 1;
        accf sims;

        if (isQK) {
            // ---- QK: sims^T[32n x 32q], full K=512, 2 interleaved chains ----
            accf se, so;
#pragma unroll
            for (int i = 0; i < 16; ++i) { se[i] = 0.f; so[i] = 0.f; }
            const int n = jn * 32 + lq;
            const unsigned short* Abase = &PatL[buf][n * DD];
            const int sw = (n & 7) << 3;
#pragma unroll
            for (int ks = 0; ks < 32; ks += 2) {
                bfrag a0 = *reinterpret_cast<const bfrag*>(Abase + ((ks * 16 + hi * 8) ^ sw));
                bfrag a1 = *reinterpret_cast<const bfrag*>(Abase + (((ks + 1) * 16 + hi * 8) ^ sw));
                se = __builtin_amdgcn_mfma_f32_32x32x16_bf16(
                    a0, *reinterpret_cast<const bfrag*>(&sfrag[ks]), se, 0, 0, 0);
                so = __builtin_amdgcn_mfma_f32_32x32x16_bf16(
                    a1, *reinterpret_cast<const bfrag*>(&sfrag[ks + 1]), so, 0, 0, 0);
            }
#pragma unroll
            for (int i = 0; i < 16; ++i) sims[i] = se[i] + so[i];
            // per-q column max over this wave's 32 n-rows
            float mx = sims[0];
#pragma unroll
            for (int i = 1; i < 16; ++i) mx = fmaxf(mx, sims[i]);
            mx = fmaxf(mx, __shfl_xor(mx, 32, 64));
            if (hi == 0) Marr[jn][q] = mx;
        }
        __syncthreads();   // B1: Marr ready; PatL[buf] fully read; Pr/Alr consumed

        // ---- all waves: ds_write staged tile t+1 into buf^1 ----
        if (tile + 1 < NTILES) {
#pragma unroll
            for (int i = 0; i < 8; ++i) {
                const int r = w * 8 + i;
                *reinterpret_cast<uint4*>(&PatL[buf ^ 1][r * DD + ln * 8]) = sg[i];
            }
        }

        if (isQK) {
            // ---- softmax for this wave's 32n x 32q block ----
            const float tm    = fmaxf(Marr[0][q], Marr[1][q]);
            const float m_new = fmaxf(m_run, tm);
            const float alq   = __expf(m_run - m_new);
            float p[16];
            float psum = 0.f;
#pragma unroll
            for (int i = 0; i < 16; ++i) { p[i] = __expf(sims[i] - m_new); psum += p[i]; }
            psum += __shfl_xor(psum, 32, 64);
            l_run = l_run * alq + psum;
            m_run = m_new;
            if (hi == 0 && jn == 0) Alr[q] = alq;
#pragma unroll
            for (int r = 0; r < 4; ++r) {
                ushort4 pk;
                pk.x = f2bf(p[4 * r + 0]); pk.y = f2bf(p[4 * r + 1]);
                pk.z = f2bf(p[4 * r + 2]); pk.w = f2bf(p[4 * r + 3]);
                const int n0  = jn * 32 + 8 * r + 4 * hi;
                const int off = (q * NT + n0) ^ ((q & 7) << 3);
                *reinterpret_cast<ushort4*>(&Pr[off]) = pk;
            }
        }
        __syncthreads();   // B2: Pr/Alr ready; PatL[buf^1] staged for QK(t+1)

        // ---- all waves: issue staging loads for tile t+2 ----
        if (tile + 2 < NTILES) {
            const unsigned short* src = pat + (nbase + (size_t)(tile + 2) * NT) * DD;
#pragma unroll
            for (int i = 0; i < 8; ++i) {
                const int r = w * 8 + i;
                sg[i] = *reinterpret_cast<const uint4*>(src + r * DD + ((ln * 8) ^ ((r & 7) << 3)));
            }
        }

        if (!isQK && do_pv) {
            // ---- PV: out^T[128d x 64q] += patT-frags(t) @ Pr(t) ----
            const float a0 = Alr[lq], a1 = Alr[32 + lq];
#pragma unroll
            for (int dt = 0; dt < 4; ++dt)
#pragma unroll
                for (int i = 0; i < 16; ++i) { acc[dt][0][i] *= a0; acc[dt][1][i] *= a1; }

            const size_t ncol = nbase + (size_t)tile * NT;
#pragma unroll
            for (int ks = 0; ks < 4; ++ks) {
                bfrag b0, b1;
                {
                    const int o0 = ((lq) * NT + ks * 16 + hi * 8) ^ ((lq & 7) << 3);
                    const int o1 = ((32 + lq) * NT + ks * 16 + hi * 8) ^ (((32 + lq) & 7) << 3);
                    b0 = *reinterpret_cast<const bfrag*>(&Pr[o0]);
                    b1 = *reinterpret_cast<const bfrag*>(&Pr[o1]);
                }
#pragma unroll
                for (int dt = 0; dt < 4; ++dt) {
                    const size_t drow = (size_t)(pw * 128 + dt * 32 + lq);
                    uint4 ga = *reinterpret_cast<const uint4*>(
                        patT + drow * NP + ncol + ks * 16 + hi * 8);
                    acc[dt][0] = __builtin_amdgcn_mfma_f32_32x32x16_bf16(
                        *reinterpret_cast<const bfrag*>(&ga), b0, acc[dt][0], 0, 0, 0);
                    acc[dt][1] = __builtin_amdgcn_mfma_f32_32x32x16_bf16(
                        *reinterpret_cast<const bfrag*>(&ga), b1, acc[dt][1], 0, 0, 0);
                }
            }
        }
    }

    // ---------- epilogue: merge l across jn, write partials ----------
    if (isQK && hi == 0) Marr[jn][q] = l_run;
    __syncthreads();
    if (isQK && jn == 0 && hi == 0) {
        mpart[chunk * BQ + qb0 + q] = m_run;
        lpart[chunk * BQ + qb0 + q] = Marr[0][q] + Marr[1][q];
    }
    if (!isQK && do_pv) {
        float* ap = accp + (size_t)chunk * DD * BQ;
#pragma unroll
        for (int dt = 0; dt < 4; ++dt)
#pragma unroll
            for (int qt = 0; qt < 2; ++qt)
#pragma unroll
                for (int i = 0; i < 16; ++i) {
                    const int dr = pw * 128 + dt * 32 + (i & 3) + 8 * (i >> 2) + 4 * hi;
                    ap[(size_t)dr * BQ + qb0 + qt * 32 + lq] = acc[dt][qt][i];
                }
    }
}

// ---------------- combine: merge chunk partials -> next state ----------------

__global__ __launch_bounds__(256) void hopf_combine(
    const float* __restrict__ mpart, const float* __restrict__ lpart,
    const float* __restrict__ accp,
    float* __restrict__ state_next, unsigned short* __restrict__ stbf_next)
{
    __shared__ float T[64][69];
    const int t  = threadIdx.x;
    const int qb = blockIdx.x, db = blockIdx.y;   // (16, 8)
    const int q  = qb * 64 + (t & 63);
    const int dg = t >> 6;                         // 0..3

    float mv[NCHK];
    float M = -INFINITY;
#pragma unroll
    for (int c = 0; c < NCHK; ++c) { mv[c] = mpart[c * BQ + q]; M = fmaxf(M, mv[c]); }
    float wx[NCHK];
    float L = 0.f;
#pragma unroll
    for (int c = 0; c < NCHK; ++c) { wx[c] = __expf(mv[c] - M); L += lpart[c * BQ + q] * wx[c]; }
    const float invL = 1.f / L;

    float v[16];
#pragma unroll
    for (int k = 0; k < 16; ++k) v[k] = 0.f;
    for (int c = 0; c < NCHK; ++c) {
        const float* ap = accp + ((size_t)c * DD + db * 64 + dg) * BQ + q;
#pragma unroll
        for (int k = 0; k < 16; ++k) v[k] = fmaf(wx[c], ap[(size_t)(4 * k) * BQ], v[k]);
    }
#pragma unroll
    for (int k = 0; k < 16; ++k) T[t & 63][dg + 4 * k] = v[k] * invL;
    __syncthreads();
    {
        const int qo = t >> 2, ds = (t & 3) * 16;
        float o[16];
#pragma unroll
        for (int j = 0; j < 16; ++j) o[j] = T[qo][ds + j];
        float* dst = state_next + (size_t)(qb * 64 + qo) * DD + db * 64 + ds;
        unsigned short* bdst = stbf_next + (size_t)(qb * 64 + qo) * DD + db * 64 + ds;
#pragma unroll
        for (int j = 0; j < 16; ++j) dst[j] = o[j];
#pragma unroll
        for (int j = 0; j < 16; ++j) bdst[j] = f2bf(o[j]);
    }
}

// ---------------- energy ----------------

__global__ __launch_bounds__(256) void hopf_energy(
    const float* __restrict__ state_cur,
    const float* __restrict__ mpart, const float* __restrict__ lpart,
    float* __restrict__ eout)
{
    const int ln = threadIdx.x & 63, w = threadIdx.x >> 6;
    const int q  = blockIdx.x * 4 + w;
    float mv[NCHK];
    float M = -INFINITY;
#pragma unroll
    for (int c = 0; c < NCHK; ++c) { mv[c] = mpart[c * BQ + q]; M = fmaxf(M, mv[c]); }
    float L = 0.f;
#pragma unroll
    for (int c = 0; c < NCHK; ++c) L += lpart[c * BQ + q] * __expf(mv[c] - M);
    float ns = 0.f;
#pragma unroll
    for (int k = 0; k < 8; ++k) {
        const float vv = state_cur[(size_t)q * DD + ln + 64 * k];
        ns = fmaf(vv, vv, ns);
    }
#pragma unroll
    for (int mk = 1; mk < 64; mk <<= 1) ns += __shfl_xor(ns, mk, 64);
    if (ln == 0) eout[q] = -(M + __logf(L)) + 0.5f * ns;   // beta = 1
}

// ---------------- launch ----------------

extern "C" void kernel_launch(void* const* d_in, const int* in_sizes, int n_in,
                              void* d_out, int out_size, void* d_ws, size_t ws_size,
                              hipStream_t stream) {
    (void)in_sizes; (void)n_in; (void)out_size; (void)ws_size;
    const float* query    = (const float*)d_in[0];   // [1024, 512]
    const float* patterns = (const float*)d_in[1];   // [65536, 512]
    float* out = (float*)d_out;

    uint8_t* ws = (uint8_t*)d_ws;
    unsigned short* pat  = (unsigned short*)ws; ws += (size_t)NP * DD * 2;   // 67 MB
    unsigned short* patT = (unsigned short*)ws; ws += (size_t)NP * DD * 2;   // 67 MB
    float* stateA = (float*)ws; ws += (size_t)BQ * DD * 4;
    float* stateB = (float*)ws; ws += (size_t)BQ * DD * 4;
    unsigned short* stbf = (unsigned short*)ws; ws += (size_t)BQ * DD * 2;
    float* mpart = (float*)ws; ws += (size_t)NCHK * BQ * 4;
    float* lpart = (float*)ws; ws += (size_t)NCHK * BQ * 4;
    float* accp  = (float*)ws; ws += (size_t)NCHK * DD * BQ * 4;             // 32 MB

    conv_patterns<<<dim3(8192), 256, 0, stream>>>(patterns, pat, patT);
    conv_state<<<dim3(512), 256, 0, stream>>>(query, stateA, stbf);

    float* energies = out + BQ * DD;
    for (int t = 0; t <= NSTEP; ++t) {
        float* cur = (t & 1) ? stateB : stateA;
        float* nxt = (t & 1) ? stateA : stateB;
        hopf_pass<<<dim3(NCHK, NQB), 512, 0, stream>>>(pat, patT, stbf, mpart, lpart,
                                                       accp, (t < NSTEP) ? 1 : 0);
        hopf_energy<<<dim3(BQ / 4), 256, 0, stream>>>(cur, mpart, lpart, energies + t * BQ);
        if (t < NSTEP)
            hopf_combine<<<dim3(NQB, 8), 256, 0, stream>>>(mpart, lpart, accp, nxt, stbf);
    }
    hipMemcpyAsync(out, stateA, (size_t)BQ * DD * 4, hipMemcpyDeviceToDevice, stream);
}

// Round 6
// 5160.376 us; speedup vs baseline: 3.4553x; 2.4550x over previous
//
#include <hip/hip_runtime.h>
#include <hip/hip_bf16.h>
#include <stdint.h>
#include <math.h>

// Modern Hopfield retrieval. Unified 8-wave MFMA flash kernel with
// softmax-bound trick: since patterns are unit-norm, sims <= ||state_q|| = B_q,
// so p = exp(s - B_q) needs no online max -> no max exchange, no rescale,
// 2 barriers per 64-pattern tile. B=1024, N=65536, D=512, beta=1.

#define BQ    1024
#define DD    512
#define NP    65536
#define NSTEP 10
#define NCHK  16
#define CHK   4096        // NP/NCHK
#define QB    64
#define NQB   16
#define NT    64
#define NTILES 64         // CHK/NT

typedef __attribute__((ext_vector_type(8)))  short bfrag;   // 8 bf16 = 4 VGPR
typedef __attribute__((ext_vector_type(16))) float accf;    // 32x32 accumulator

__device__ __forceinline__ unsigned short f2bf(float f) {
    uint32_t u = __float_as_uint(f);
    u += 0x7FFFu + ((u >> 16) & 1u);   // RNE
    return (unsigned short)(u >> 16);
}

// ---------------- one-time converts ----------------

__global__ __launch_bounds__(256) void conv_patterns(
    const float* __restrict__ pat_f32,
    unsigned short* __restrict__ pat, unsigned short* __restrict__ patT)
{
    __shared__ unsigned short T[64][65];
    const int t  = threadIdx.x;
    const int n0 = (blockIdx.x >> 3) * 64, d0 = (blockIdx.x & 7) * 64;
    {
        const int r = t >> 2, c0 = (t & 3) * 16;
        const float* src = pat_f32 + (size_t)(n0 + r) * DD + d0 + c0;
        unsigned short loc[16];
#pragma unroll
        for (int j = 0; j < 16; ++j) loc[j] = f2bf(src[j]);
        unsigned short* d = pat + (size_t)(n0 + r) * DD + d0 + c0;
#pragma unroll
        for (int j = 0; j < 16; ++j) d[j] = loc[j];
#pragma unroll
        for (int j = 0; j < 16; ++j) T[r][c0 + j] = loc[j];
    }
    __syncthreads();
    {
        const int dl = t >> 2, nc0 = (t & 3) * 16;
        unsigned short* dst = patT + (size_t)(d0 + dl) * NP + n0 + nc0;
#pragma unroll
        for (int j = 0; j < 16; ++j) dst[j] = T[nc0 + j][dl];
    }
}

// one block per 4 query rows: copy f32, make bf16, and norm^2 partials
__global__ __launch_bounds__(256) void conv_state(
    const float* __restrict__ query, float* __restrict__ stA,
    unsigned short* __restrict__ stbf, float* __restrict__ nsqp)
{
    const int w = threadIdx.x >> 6, ln = threadIdx.x & 63;
    const int q = blockIdx.x * 4 + w;
    float ns = 0.f;
#pragma unroll
    for (int k = 0; k < 8; ++k) {
        const size_t idx = (size_t)q * DD + ln + 64 * k;
        const float v = query[idx];
        stA[idx] = v;
        stbf[idx] = f2bf(v);
        ns = fmaf(v, v, ns);
    }
#pragma unroll
    for (int mk = 1; mk < 64; mk <<= 1) ns += __shfl_xor(ns, mk, 64);
    if (ln == 0) {
        nsqp[q] = ns;
#pragma unroll
        for (int j = 1; j < 8; ++j) nsqp[j * BQ + q] = 0.f;
    }
}

// ---------------- main pass ----------------

__global__ __launch_bounds__(512, 2) void hopf_pass(
    const unsigned short* __restrict__ pat,    // [NP][DD] bf16
    const unsigned short* __restrict__ patT,   // [DD][NP] bf16
    const unsigned short* __restrict__ stbf,   // [BQ][DD] bf16
    const float* __restrict__ nsqp,            // [8][BQ] norm^2 partials (current)
    float* __restrict__ lpart,                 // [NCHK][BQ]
    float* __restrict__ accp,                  // [NCHK][DD][BQ] out^T partials
    int do_pv)
{
    __shared__ unsigned short PatL[2][NT * DD];   // 2 x 64 KB, source-swizzled
    __shared__ float Sp[NT][QB + 2];              // K-half partial sims (16.9 KB)
    __shared__ unsigned short Pr[QB * NT];        // probs bf16 [q][n], swizzled (8 KB)

    const int t  = threadIdx.x, ln = t & 63, w = t >> 6;
    const int lq = ln & 31, hi = ln >> 5;
    const int chunk = blockIdx.x, qb0 = blockIdx.y * QB;
    const size_t nbase = (size_t)chunk * CHK;
    const int jn = w & 1, jq = (w >> 1) & 1, h = w >> 2;
    const int q  = jq * 32 + lq;                   // this wave's QK query column

    // ---- softmax bound: B_q = ||state_q|| (patterns are unit-norm) ----
    float Bq = 0.f;
#pragma unroll
    for (int j = 0; j < 8; ++j) Bq += nsqp[j * BQ + qb0 + q];
    Bq = sqrtf(Bq);

    // ---- state B-frags: K-half h ----
    uint4 sfrag[16];
    {
        const unsigned short* sp = stbf + (size_t)(qb0 + q) * DD + h * 256 + hi * 8;
#pragma unroll
        for (int ks = 0; ks < 16; ++ks)
            sfrag[ks] = *reinterpret_cast<const uint4*>(sp + ks * 16);
    }

    // ---- PV accumulator (this wave owns d = w*64 + dt*32 rows) ----
    accf acc[2][2];
#pragma unroll
    for (int a = 0; a < 2; ++a)
#pragma unroll
        for (int b = 0; b < 2; ++b)
#pragma unroll
            for (int i = 0; i < 16; ++i) acc[a][b][i] = 0.f;

    float l_run = 0.f;
    uint4 sg[8];

    // ---- prologue: tile 0 -> buf0 (via regs), tile 1 -> sg ----
    {
        const unsigned short* src = pat + nbase * DD;
#pragma unroll
        for (int i = 0; i < 8; ++i) {
            const int r = w * 8 + i;
            sg[i] = *reinterpret_cast<const uint4*>(src + r * DD + ((ln * 8) ^ ((r & 7) << 3)));
        }
#pragma unroll
        for (int i = 0; i < 8; ++i) {
            const int r = w * 8 + i;
            *reinterpret_cast<uint4*>(&PatL[0][r * DD + ln * 8]) = sg[i];
        }
        const unsigned short* src1 = pat + (nbase + NT) * DD;
#pragma unroll
        for (int i = 0; i < 8; ++i) {
            const int r = w * 8 + i;
            sg[i] = *reinterpret_cast<const uint4*>(src1 + r * DD + ((ln * 8) ^ ((r & 7) << 3)));
        }
    }
    __syncthreads();

    for (int tile = 0; tile < NTILES; ++tile) {
        const int buf = tile & 1;

        // ---- phase 1: QK MFMAs (K-half h), h1 waves post partials ----
        accf sims;
#pragma unroll
        for (int i = 0; i < 16; ++i) sims[i] = 0.f;
        {
            const int n = jn * 32 + lq;
            const unsigned short* Abase = &PatL[buf][n * DD];
            const int sw   = (n & 7) << 3;
            const int boff = h * 256 + hi * 8;
#pragma unroll
            for (int ks = 0; ks < 16; ++ks) {
                bfrag a = *reinterpret_cast<const bfrag*>(Abase + ((boff + ks * 16) ^ sw));
                sims = __builtin_amdgcn_mfma_f32_32x32x16_bf16(
                    a, *reinterpret_cast<const bfrag*>(&sfrag[ks]), sims, 0, 0, 0);
            }
        }
        if (h == 1) {
#pragma unroll
            for (int i = 0; i < 16; ++i) {
                const int n = jn * 32 + (i & 3) + 8 * (i >> 2) + 4 * hi;
                Sp[n][jq * 32 + lq] = sims[i];
            }
        }
        __syncthreads();   // B1: Sp ready; PatL[buf^1] free for staging writes

        // ---- phase 2: stage tile t+1; h0 waves do bound-softmax + Pr ----
        if (tile + 1 < NTILES) {
#pragma unroll
            for (int i = 0; i < 8; ++i) {
                const int r = w * 8 + i;
                *reinterpret_cast<uint4*>(&PatL[buf ^ 1][r * DD + ln * 8]) = sg[i];
            }
        }
        if (h == 0) {
            float p[16];
            float psum = 0.f;
#pragma unroll
            for (int i = 0; i < 16; ++i) {
                const int n = jn * 32 + (i & 3) + 8 * (i >> 2) + 4 * hi;
                const float s = sims[i] + Sp[n][jq * 32 + lq];
                p[i] = __expf(s - Bq);
                psum += p[i];
            }
            psum += __shfl_xor(psum, 32, 64);
            l_run += psum;
            if (do_pv) {
#pragma unroll
                for (int r = 0; r < 4; ++r) {
                    ushort4 pk;
                    pk.x = f2bf(p[4 * r + 0]); pk.y = f2bf(p[4 * r + 1]);
                    pk.z = f2bf(p[4 * r + 2]); pk.w = f2bf(p[4 * r + 3]);
                    const int n0  = jn * 32 + 8 * r + 4 * hi;
                    const int off = (q * NT + n0) ^ ((q & 7) << 3);
                    *reinterpret_cast<ushort4*>(&Pr[off]) = pk;
                }
            }
        }
        __syncthreads();   // B2: Pr ready; PatL[buf^1] staged

        // ---- phase 3: issue staging loads for t+2, then PV ----
        if (tile + 2 < NTILES) {
            const unsigned short* src = pat + (nbase + (size_t)(tile + 2) * NT) * DD;
#pragma unroll
            for (int i = 0; i < 8; ++i) {
                const int r = w * 8 + i;
                sg[i] = *reinterpret_cast<const uint4*>(src + r * DD + ((ln * 8) ^ ((r & 7) << 3)));
            }
        }
        if (do_pv) {
            const size_t ncol = nbase + (size_t)tile * NT;
#pragma unroll
            for (int ks = 0; ks < 4; ++ks) {
                bfrag b0, b1;
                {
                    const int o0 = ((lq) * NT + ks * 16 + hi * 8) ^ ((lq & 7) << 3);
                    const int o1 = ((32 + lq) * NT + ks * 16 + hi * 8) ^ (((32 + lq) & 7) << 3);
                    b0 = *reinterpret_cast<const bfrag*>(&Pr[o0]);
                    b1 = *reinterpret_cast<const bfrag*>(&Pr[o1]);
                }
#pragma unroll
                for (int dt = 0; dt < 2; ++dt) {
                    const size_t drow = (size_t)(w * 64 + dt * 32 + lq);
                    uint4 ga = *reinterpret_cast<const uint4*>(
                        patT + drow * NP + ncol + ks * 16 + hi * 8);
                    acc[dt][0] = __builtin_amdgcn_mfma_f32_32x32x16_bf16(
                        *reinterpret_cast<const bfrag*>(&ga), b0, acc[dt][0], 0, 0, 0);
                    acc[dt][1] = __builtin_amdgcn_mfma_f32_32x32x16_bf16(
                        *reinterpret_cast<const bfrag*>(&ga), b1, acc[dt][1], 0, 0, 0);
                }
            }
        }
    }

    // ---- epilogue: merge l across jn halves (reuse Sp rows 0,1) ----
    if (h == 0 && hi == 0) Sp[jn][q] = l_run;
    __syncthreads();
    if (w == 0) lpart[chunk * BQ + qb0 + ln] = Sp[0][ln] + Sp[1][ln];
    if (do_pv) {
        float* ap = accp + (size_t)chunk * DD * BQ;
#pragma unroll
        for (int dt = 0; dt < 2; ++dt)
#pragma unroll
            for (int qt = 0; qt < 2; ++qt)
#pragma unroll
                for (int i = 0; i < 16; ++i) {
                    const int dr = w * 64 + dt * 32 + (i & 3) + 8 * (i >> 2) + 4 * hi;
                    ap[(size_t)dr * BQ + qb0 + qt * 32 + lq] = acc[dt][qt][i];
                }
    }
}

// ---------------- combine: sum chunk partials -> next state + norms ----------------

__global__ __launch_bounds__(512) void hopf_combine(
    const float* __restrict__ lpart, const float* __restrict__ accp,
    float* __restrict__ state_next, unsigned short* __restrict__ stbf_next,
    float* __restrict__ nsqp_next)
{
    __shared__ float Nsm[8][64];
    const int w  = threadIdx.x >> 6, ln = threadIdx.x & 63;
    const int qb = blockIdx.x, db = blockIdx.y;   // (16, 8)
    const int q  = qb * 64 + ln;
    const int d0 = db * 64 + w * 8;

    float L = 0.f;
#pragma unroll
    for (int c = 0; c < NCHK; ++c) L += lpart[c * BQ + q];
    const float invL = 1.f / L;

    float v[8];
#pragma unroll
    for (int k = 0; k < 8; ++k) v[k] = 0.f;
    for (int c = 0; c < NCHK; ++c) {
        const float* ap = accp + ((size_t)c * DD + d0) * BQ + q;
#pragma unroll
        for (int k = 0; k < 8; ++k) v[k] += ap[(size_t)k * BQ];
    }
    float ns = 0.f;
#pragma unroll
    for (int k = 0; k < 8; ++k) { v[k] *= invL; ns = fmaf(v[k], v[k], ns); }

    float* dst = state_next + (size_t)q * DD + d0;
    unsigned short* bdst = stbf_next + (size_t)q * DD + d0;
#pragma unroll
    for (int k = 0; k < 8; ++k) dst[k] = v[k];
#pragma unroll
    for (int k = 0; k < 8; ++k) bdst[k] = f2bf(v[k]);

    Nsm[w][ln] = ns;
    __syncthreads();
    if (w == 0) {
        float s = 0.f;
#pragma unroll
        for (int j = 0; j < 8; ++j) s += Nsm[j][ln];
        nsqp_next[db * BQ + q] = s;
    }
}

// ---------------- energy ----------------

__global__ __launch_bounds__(256) void hopf_energy(
    const float* __restrict__ lpart, const float* __restrict__ nsqp,
    float* __restrict__ eout)
{
    const int q = blockIdx.x * 256 + threadIdx.x;   // grid 4
    float L = 0.f;
#pragma unroll
    for (int c = 0; c < NCHK; ++c) L += lpart[c * BQ + q];
    float ns = 0.f;
#pragma unroll
    for (int j = 0; j < 8; ++j) ns += nsqp[j * BQ + q];
    // lse = B + log(sum exp(s-B)), B = sqrt(ns); beta = 1
    eout[q] = -(sqrtf(ns) + __logf(L)) + 0.5f * ns;
}

// ---------------- launch ----------------

extern "C" void kernel_launch(void* const* d_in, const int* in_sizes, int n_in,
                              void* d_out, int out_size, void* d_ws, size_t ws_size,
                              hipStream_t stream) {
    (void)in_sizes; (void)n_in; (void)out_size; (void)ws_size;
    const float* query    = (const float*)d_in[0];   // [1024, 512]
    const float* patterns = (const float*)d_in[1];   // [65536, 512]
    float* out = (float*)d_out;

    uint8_t* ws = (uint8_t*)d_ws;
    unsigned short* pat  = (unsigned short*)ws; ws += (size_t)NP * DD * 2;   // 67 MB
    unsigned short* patT = (unsigned short*)ws; ws += (size_t)NP * DD * 2;   // 67 MB
    float* stateA = (float*)ws; ws += (size_t)BQ * DD * 4;
    float* stateB = (float*)ws; ws += (size_t)BQ * DD * 4;
    unsigned short* stbf = (unsigned short*)ws; ws += (size_t)BQ * DD * 2;
    float* lpart = (float*)ws; ws += (size_t)NCHK * BQ * 4;
    float* nsqA  = (float*)ws; ws += (size_t)8 * BQ * 4;
    float* nsqB  = (float*)ws; ws += (size_t)8 * BQ * 4;
    float* accp  = (float*)ws; ws += (size_t)NCHK * DD * BQ * 4;             // 32 MB

    conv_patterns<<<dim3(8192), 256, 0, stream>>>(patterns, pat, patT);
    conv_state<<<dim3(BQ / 4), 256, 0, stream>>>(query, stateA, stbf, nsqA);

    float* energies = out + BQ * DD;
    for (int t = 0; t <= NSTEP; ++t) {
        float* nxt     = (t & 1) ? stateA : stateB;
        float* nsq_cur = (t & 1) ? nsqB : nsqA;
        float* nsq_nxt = (t & 1) ? nsqA : nsqB;
        hopf_pass<<<dim3(NCHK, NQB), 512, 0, stream>>>(pat, patT, stbf, nsq_cur,
                                                       lpart, accp, (t < NSTEP) ? 1 : 0);
        hopf_energy<<<dim3(BQ / 256), 256, 0, stream>>>(lpart, nsq_cur, energies + t * BQ);
        if (t < NSTEP)
            hopf_combine<<<dim3(NQB, 8), 512, 0, stream>>>(lpart, accp, nxt, stbf, nsq_nxt);
    }
    // state after step 9 lives in stateA (combine at t=9 wrote nxt=stateA)
    hipMemcpyAsync(out, stateA, (size_t)BQ * DD * 4, hipMemcpyDeviceToDevice, stream);
}